// Round 1
// baseline (508.194 us; speedup 1.0000x reference)
//
#include <hip/hip_runtime.h>

// Splat conv (full true convolution):
//   out[oi, oj] = sum_{di,dj in [0,5)} in[oi-di, oj-dj] * f[di][dj]
// in:  8192 x 8192 fp32
// out: 8196 x 8196 fp32  (no bias in forward)
//
// Memory-bound (~537 MB traffic, ~85 us floor at 6.3 TB/s).
// Each thread: one float4 of output (4 cols), needs 8 contiguous input cols
// = two aligned float4 loads per input row, over 5 rows.

#define IN_H 8192
#define IN_W 8192
#define OUT_H 8196
#define OUT_W 8196
#define NG 2049  // OUT_W / 4 groups of float4 per output row

__global__ __launch_bounds__(256) void splat_conv_kernel(
    const float* __restrict__ in, const float* __restrict__ flt,
    float* __restrict__ out) {
  const int g = blockIdx.x * 64 + threadIdx.x;   // float4 group in row
  const int row = blockIdx.y * 4 + threadIdx.y;  // output row
  if (g >= NG) return;

  // Filter: 25 uniform loads (L1-broadcast / scalarized by compiler).
  float f[25];
#pragma unroll
  for (int i = 0; i < 25; ++i) f[i] = flt[i];

  const int c0 = 4 * g - 4;         // base col of first float4 load
  const bool lo_ok = (g != 0);      // cols 4g-4 .. 4g-1 in range?
  const bool hi_ok = (g != NG - 1); // cols 4g   .. 4g+3 in range?

  float acc0 = 0.f, acc1 = 0.f, acc2 = 0.f, acc3 = 0.f;

#pragma unroll
  for (int dr = 0; dr < 5; ++dr) {
    const int r = row + dr - 4;  // input row (filter row di = 4 - dr)
    float4 a = make_float4(0.f, 0.f, 0.f, 0.f);
    float4 b = make_float4(0.f, 0.f, 0.f, 0.f);
    if (r >= 0 && r < IN_H) {
      const float* rp = in + (size_t)r * IN_W;
      if (lo_ok) a = *(const float4*)(rp + c0);
      if (hi_ok) b = *(const float4*)(rp + c0 + 4);
    }
    float x[8];
    x[0] = a.x; x[1] = a.y; x[2] = a.z; x[3] = a.w;
    x[4] = b.x; x[5] = b.y; x[6] = b.z; x[7] = b.w;

    const int di = 4 - dr;
#pragma unroll
    for (int dj = 0; dj < 5; ++dj) {
      const float w = f[di * 5 + dj];
      // output col o = 4g + k uses input col o - dj = c0 + (k + 4 - dj)
      acc0 += x[0 + 4 - dj] * w;
      acc1 += x[1 + 4 - dj] * w;
      acc2 += x[2 + 4 - dj] * w;
      acc3 += x[3 + 4 - dj] * w;
    }
  }

  float4 o = make_float4(acc0, acc1, acc2, acc3);
  *(float4*)(out + (size_t)row * OUT_W + 4 * g) = o;  // 16B-aligned
}

extern "C" void kernel_launch(void* const* d_in, const int* in_sizes, int n_in,
                              void* d_out, int out_size, void* d_ws,
                              size_t ws_size, hipStream_t stream) {
  const float* in = (const float*)d_in[0];
  const float* flt = (const float*)d_in[1];
  // d_in[2] = bias: NOT used by the forward reference.
  float* out = (float*)d_out;

  dim3 block(64, 4);                    // 256 threads
  dim3 grid((NG + 63) / 64, OUT_H / 4); // 33 x 2049
  splat_conv_kernel<<<grid, block, 0, stream>>>(in, flt, out);
}